// Round 1
// baseline (805.822 us; speedup 1.0000x reference)
//
#include <hip/hip_runtime.h>
#include <stdint.h>

#define DEV static __device__ __forceinline__

typedef __attribute__((ext_vector_type(8))) short bf16x8;
typedef __attribute__((ext_vector_type(4))) float f32x4;

constexpr int Bc = 8, Tc = 2048, Cc = 1024, Hc = 16, Dc = 64;

DEV ushort f2bf(float f) {
  union { float f; uint32_t u; } x{f};
  uint32_t r = (x.u + 0x7FFFu + ((x.u >> 16) & 1u)) >> 16;
  return (ushort)r;
}

DEV void gload16(const ushort* g, ushort* l) {
  __builtin_amdgcn_global_load_lds(
      (const __attribute__((address_space(1))) unsigned int*)g,
      (__attribute__((address_space(3))) unsigned int*)l, 16, 0, 0);
}

DEV f32x4 mfma16(bf16x8 a, bf16x8 b, f32x4 c) {
  return __builtin_amdgcn_mfma_f32_16x16x32_bf16(a, b, c, 0, 0, 0);
}

// ---------------- converts ----------------
__global__ __launch_bounds__(256) void k_conv_x(const float* __restrict__ x, ushort* __restrict__ xb) {
  int i = blockIdx.x * 256 + threadIdx.x;
  float4 v = ((const float4*)x)[i];
  ushort4 o = make_ushort4(f2bf(v.x), f2bf(v.y), f2bf(v.z), f2bf(v.w));
  ((ushort4*)xb)[i] = o;
}

__global__ __launch_bounds__(256) void k_conv_wqkv(const float* __restrict__ wq, const float* __restrict__ wk,
                                                   const float* __restrict__ wv, ushort* __restrict__ wt) {
  int i = blockIdx.x * 256 + threadIdx.x;   // 0 .. 3072*1024-1
  int c = i & 1023;
  int n = i >> 10;
  int which = n >> 10;
  int rem = n & 1023;
  int h = rem >> 6, d = rem & 63;
  const float* src = which == 0 ? wq : (which == 1 ? wk : wv);
  float v = src[((size_t)h * 1024 + c) * 64 + d];
  if (which == 0) v *= 0.03125f;  // fold C^-0.5 = 1/32 into wq
  wt[i] = f2bf(v);
}

__global__ __launch_bounds__(256) void k_conv_wproj(const float* __restrict__ wp, ushort* __restrict__ wt) {
  int i = blockIdx.x * 256 + threadIdx.x;   // 0 .. 1024*1024-1
  int n = i >> 10, k = i & 1023;
  wt[i] = f2bf(wp[(size_t)k * 1024 + n]);
}

// ---------------- shared GEMM mainloop: 128x128 tile, BK=64, K=1024 ----------------
DEV void gemm_main(const ushort* __restrict__ A, const ushort* __restrict__ BT,
                   int m0, int n0, int tid, ushort* lds_a, ushort* lds_b,
                   f32x4 (&acc)[4][4]) {
  const int lane = tid & 63, wid = tid >> 6;
  const int lr = lane & 15, lg = lane >> 4;
  const int wm = wid >> 1, wn = wid & 1;
  for (int kt = 0; kt < 16; ++kt) {
#pragma unroll
    for (int r = 0; r < 4; ++r) {
      int flat = r * 256 + tid;      // 0..1023 chunks of 16B
      int row = flat >> 3, c8 = flat & 7;
      gload16(&A[(size_t)(m0 + row) * 1024 + kt * 64 + c8 * 8], &lds_a[flat * 8]);
      gload16(&BT[(size_t)(n0 + row) * 1024 + kt * 64 + c8 * 8], &lds_b[flat * 8]);
    }
    __syncthreads();
#pragma unroll
    for (int kc = 0; kc < 2; ++kc) {
      bf16x8 af[4], bfr[4];
#pragma unroll
      for (int mf = 0; mf < 4; ++mf)
        af[mf] = *(const bf16x8*)&lds_a[(wm * 64 + mf * 16 + lr) * 64 + kc * 32 + lg * 8];
#pragma unroll
      for (int nf = 0; nf < 4; ++nf)
        bfr[nf] = *(const bf16x8*)&lds_b[(wn * 64 + nf * 16 + lr) * 64 + kc * 32 + lg * 8];
#pragma unroll
      for (int mf = 0; mf < 4; ++mf)
#pragma unroll
        for (int nf = 0; nf < 4; ++nf)
          acc[mf][nf] = mfma16(af[mf], bfr[nf], acc[mf][nf]);
    }
    __syncthreads();
  }
}

// ---------------- QKV projection GEMM ----------------
__global__ __launch_bounds__(256) void k_gemm_qkv(const ushort* __restrict__ xb, const ushort* __restrict__ wt,
                                                  ushort* __restrict__ qws, ushort* __restrict__ kws,
                                                  ushort* __restrict__ vws) {
  __shared__ ushort lds_a[128 * 64];
  __shared__ ushort lds_b[128 * 64];
  const int tid = threadIdx.x;
  const int m0 = blockIdx.x * 128, n0 = blockIdx.y * 128;
  f32x4 acc[4][4];
  f32x4 z = {0.f, 0.f, 0.f, 0.f};
  for (int i = 0; i < 4; ++i) for (int j = 0; j < 4; ++j) acc[i][j] = z;
  gemm_main(xb, wt, m0, n0, tid, lds_a, lds_b, acc);
  const int lane = tid & 63, wid = tid >> 6;
  const int lr = lane & 15, lg = lane >> 4;
  const int wm = wid >> 1, wn = wid & 1;
#pragma unroll
  for (int mf = 0; mf < 4; ++mf)
#pragma unroll
    for (int nf = 0; nf < 4; ++nf)
#pragma unroll
      for (int r = 0; r < 4; ++r) {
        int m = m0 + wm * 64 + mf * 16 + lg * 4 + r;
        int n = n0 + wn * 64 + nf * 16 + lr;
        int which = n >> 10, rem = n & 1023;
        int h = rem >> 6, d = rem & 63;
        int b = m >> 11, t = m & 2047;
        ushort* dst = which == 0 ? qws : (which == 1 ? kws : vws);
        dst[((size_t)(b * Hc + h) * Tc + t) * 64 + d] = f2bf(acc[mf][nf][r]);
      }
}

// ---------------- V transpose: (B,H,T,D) -> (B,H,D,T) ----------------
__global__ __launch_bounds__(256) void k_vtrans(const ushort* __restrict__ v, ushort* __restrict__ vt) {
  __shared__ ushort lds[64][68];
  const int t0 = blockIdx.x * 64;
  const int bh = blockIdx.y;
  const int tid = threadIdx.x;
  const ushort* src = v + (size_t)bh * Tc * 64;
  ushort* dst = vt + (size_t)bh * 64 * Tc;
#pragma unroll
  for (int j = 0; j < 4; ++j) {
    int flat = j * 256 + tid;
    int row = flat >> 4, cg = flat & 15;
    ushort4 x = *(const ushort4*)&src[(size_t)(t0 + row) * 64 + cg * 4];
    lds[row][cg * 4 + 0] = x.x; lds[row][cg * 4 + 1] = x.y;
    lds[row][cg * 4 + 2] = x.z; lds[row][cg * 4 + 3] = x.w;
  }
  __syncthreads();
#pragma unroll
  for (int j = 0; j < 4; ++j) {
    int flat = j * 256 + tid;
    int d = flat >> 4, tg = flat & 15;
    ushort4 x = make_ushort4(lds[tg * 4 + 0][d], lds[tg * 4 + 1][d], lds[tg * 4 + 2][d], lds[tg * 4 + 3][d]);
    *(ushort4*)&dst[(size_t)d * Tc + t0 + tg * 4] = x;
  }
}

// ---------------- flash attention (causal) ----------------
__global__ __launch_bounds__(256) void k_attn(const ushort* __restrict__ qws, const ushort* __restrict__ kws,
                                              const ushort* __restrict__ vtws, ushort* __restrict__ att) {
  const int q0 = blockIdx.x * 128;
  const int bh = blockIdx.y;
  const int tid = threadIdx.x, lane = tid & 63, wid = tid >> 6;
  const int lr = lane & 15, lg = lane >> 4;

  __shared__ ushort lds_k[64 * 72];
  __shared__ ushort lds_vt[64 * 72];
  __shared__ ushort lds_p[4][32 * 72];

  const ushort* qbase = qws + (size_t)bh * Tc * 64;
  const ushort* kbase = kws + (size_t)bh * Tc * 64;
  const ushort* vtbase = vtws + (size_t)bh * 64 * Tc;

  const int qrow = q0 + wid * 32;

  bf16x8 qa[2][2];
#pragma unroll
  for (int qf = 0; qf < 2; ++qf)
#pragma unroll
    for (int kc = 0; kc < 2; ++kc)
      qa[qf][kc] = *(const bf16x8*)&qbase[(size_t)(qrow + qf * 16 + lr) * 64 + kc * 32 + lg * 8];

  f32x4 o[2][4];
  float m_[2][4], l_[2][4];
  f32x4 z = {0.f, 0.f, 0.f, 0.f};
#pragma unroll
  for (int qf = 0; qf < 2; ++qf) {
#pragma unroll
    for (int df = 0; df < 4; ++df) o[qf][df] = z;
#pragma unroll
    for (int r = 0; r < 4; ++r) { m_[qf][r] = -1e30f; l_[qf][r] = 0.f; }
  }

  const int ntiles = q0 / 64 + 2;
  const int qgmax = qrow + 31;

  for (int it = 0; it < ntiles; ++it) {
    const int s0 = it * 64;
    __syncthreads();
#pragma unroll
    for (int r = 0; r < 2; ++r) {
      int flat = r * 256 + tid;     // 0..511 chunks of 8 elems
      int row = flat >> 3, c8 = flat & 7;
      *(int4*)&lds_k[row * 72 + c8 * 8] = *(const int4*)&kbase[(size_t)(s0 + row) * 64 + c8 * 8];
      *(int4*)&lds_vt[row * 72 + c8 * 8] = *(const int4*)&vtbase[(size_t)row * Tc + s0 + c8 * 8];
    }
    __syncthreads();
    if (s0 > qgmax) continue;  // fully masked for this wave

    f32x4 sacc[2][4];
#pragma unroll
    for (int qf = 0; qf < 2; ++qf)
#pragma unroll
      for (int sf = 0; sf < 4; ++sf) sacc[qf][sf] = z;

#pragma unroll
    for (int kc = 0; kc < 2; ++kc) {
      bf16x8 kb[4];
#pragma unroll
      for (int sf = 0; sf < 4; ++sf)
        kb[sf] = *(const bf16x8*)&lds_k[(sf * 16 + lr) * 72 + kc * 32 + lg * 8];
#pragma unroll
      for (int qf = 0; qf < 2; ++qf)
#pragma unroll
        for (int sf = 0; sf < 4; ++sf)
          sacc[qf][sf] = mfma16(qa[qf][kc], kb[sf], sacc[qf][sf]);
    }

    if (s0 + 63 > qrow) {  // causal masking needed in this tile
#pragma unroll
      for (int qf = 0; qf < 2; ++qf)
#pragma unroll
        for (int sf = 0; sf < 4; ++sf)
#pragma unroll
          for (int r = 0; r < 4; ++r) {
            int qg = qrow + qf * 16 + lg * 4 + r;
            int sg = s0 + sf * 16 + lr;
            if (sg > qg) sacc[qf][sf][r] = -1e30f;
          }
    }

#pragma unroll
    for (int qf = 0; qf < 2; ++qf)
#pragma unroll
      for (int r = 0; r < 4; ++r) {
        float tmax = fmaxf(fmaxf(sacc[qf][0][r], sacc[qf][1][r]), fmaxf(sacc[qf][2][r], sacc[qf][3][r]));
        tmax = fmaxf(tmax, __shfl_xor(tmax, 1));
        tmax = fmaxf(tmax, __shfl_xor(tmax, 2));
        tmax = fmaxf(tmax, __shfl_xor(tmax, 4));
        tmax = fmaxf(tmax, __shfl_xor(tmax, 8));
        float mold = m_[qf][r];
        float mnew = fmaxf(mold, tmax);
        float sc = __expf(mold - mnew);
        m_[qf][r] = mnew;
        float ps = 0.f;
#pragma unroll
        for (int sf = 0; sf < 4; ++sf) {
          float p = __expf(sacc[qf][sf][r] - mnew);
          sacc[qf][sf][r] = p;
          ps += p;
        }
        ps += __shfl_xor(ps, 1); ps += __shfl_xor(ps, 2);
        ps += __shfl_xor(ps, 4); ps += __shfl_xor(ps, 8);
        l_[qf][r] = l_[qf][r] * sc + ps;
#pragma unroll
        for (int df = 0; df < 4; ++df) o[qf][df][r] *= sc;
      }

    ushort* pl = lds_p[wid];
#pragma unroll
    for (int qf = 0; qf < 2; ++qf)
#pragma unroll
      for (int sf = 0; sf < 4; ++sf)
#pragma unroll
        for (int r = 0; r < 4; ++r)
          pl[(qf * 16 + lg * 4 + r) * 72 + sf * 16 + lr] = f2bf(sacc[qf][sf][r]);

#pragma unroll
    for (int kc = 0; kc < 2; ++kc) {
      bf16x8 pa[2], vb[4];
#pragma unroll
      for (int qf = 0; qf < 2; ++qf)
        pa[qf] = *(const bf16x8*)&pl[(qf * 16 + lr) * 72 + kc * 32 + lg * 8];
#pragma unroll
      for (int df = 0; df < 4; ++df)
        vb[df] = *(const bf16x8*)&lds_vt[(df * 16 + lr) * 72 + kc * 32 + lg * 8];
#pragma unroll
      for (int qf = 0; qf < 2; ++qf)
#pragma unroll
        for (int df = 0; df < 4; ++df)
          o[qf][df] = mfma16(pa[qf], vb[df], o[qf][df]);
    }
  }

  const int b = bh >> 4, h = bh & 15;
#pragma unroll
  for (int qf = 0; qf < 2; ++qf)
#pragma unroll
    for (int df = 0; df < 4; ++df)
#pragma unroll
      for (int r = 0; r < 4; ++r) {
        int qg = qrow + qf * 16 + lg * 4 + r;
        int d = df * 16 + lr;
        float val = o[qf][df][r] / l_[qf][r];
        att[(size_t)(b * Tc + qg) * 1024 + h * 64 + d] = f2bf(val);
      }
}

// ---------------- output projection GEMM (+bias, fp32 out) ----------------
__global__ __launch_bounds__(256) void k_gemm_proj(const ushort* __restrict__ attb, const ushort* __restrict__ wt,
                                                   const float* __restrict__ bias, float* __restrict__ out) {
  __shared__ ushort lds_a[128 * 64];
  __shared__ ushort lds_b[128 * 64];
  const int tid = threadIdx.x;
  const int m0 = blockIdx.x * 128, n0 = blockIdx.y * 128;
  f32x4 acc[4][4];
  f32x4 z = {0.f, 0.f, 0.f, 0.f};
  for (int i = 0; i < 4; ++i) for (int j = 0; j < 4; ++j) acc[i][j] = z;
  gemm_main(attb, wt, m0, n0, tid, lds_a, lds_b, acc);
  const int lane = tid & 63, wid = tid >> 6;
  const int lr = lane & 15, lg = lane >> 4;
  const int wm = wid >> 1, wn = wid & 1;
#pragma unroll
  for (int mf = 0; mf < 4; ++mf)
#pragma unroll
    for (int nf = 0; nf < 4; ++nf)
#pragma unroll
      for (int r = 0; r < 4; ++r) {
        int m = m0 + wm * 64 + mf * 16 + lg * 4 + r;
        int n = n0 + wn * 64 + nf * 16 + lr;
        out[(size_t)m * 1024 + n] = acc[mf][nf][r] + bias[n];
      }
}

extern "C" void kernel_launch(void* const* d_in, const int* in_sizes, int n_in,
                              void* d_out, int out_size, void* d_ws, size_t ws_size,
                              hipStream_t stream) {
  const float* x  = (const float*)d_in[0];
  const float* wq = (const float*)d_in[1];
  const float* wk = (const float*)d_in[2];
  const float* wv = (const float*)d_in[3];
  const float* wp = (const float*)d_in[4];
  const float* bp = (const float*)d_in[5];
  float* out = (float*)d_out;

  char* ws = (char*)d_ws;
  size_t off = 0;
  auto alloc = [&](size_t bytes) { char* p = ws + off; off += (bytes + 255) & ~255ull; return p; };
  ushort* xb   = (ushort*)alloc(16384ull * 1024 * 2);
  ushort* wqkv = (ushort*)alloc(3072ull * 1024 * 2);
  ushort* wpt  = (ushort*)alloc(1024ull * 1024 * 2);
  ushort* qws  = (ushort*)alloc(16384ull * 1024 * 2);
  ushort* kws  = (ushort*)alloc(16384ull * 1024 * 2);
  ushort* vws  = (ushort*)alloc(16384ull * 1024 * 2);
  ushort* vtws = (ushort*)alloc(16384ull * 1024 * 2);
  ushort* attb = xb;  // reuse: xb dead after k_gemm_qkv

  k_conv_x<<<16384, 256, 0, stream>>>(x, xb);
  k_conv_wqkv<<<12288, 256, 0, stream>>>(wq, wk, wv, wqkv);
  k_conv_wproj<<<4096, 256, 0, stream>>>(wp, wpt);
  k_gemm_qkv<<<dim3(128, 24), 256, 0, stream>>>(xb, wqkv, qws, kws, vws);
  k_vtrans<<<dim3(32, 128), 256, 0, stream>>>(vws, vtws);
  k_attn<<<dim3(16, 128), 256, 0, stream>>>(qws, kws, vtws, attb);
  k_gemm_proj<<<dim3(128, 8), 256, 0, stream>>>(attb, wpt, bp, out);
}